// Round 2
// baseline (437.246 us; speedup 1.0000x reference)
//
#include <hip/hip_runtime.h>
#include <stdint.h>

#define E_   2048
#define HQ_  16
#define HK_  4
#define D_   128
#define G_   4
#define KVE_ 512
#define B_   2
#define N_   2048
#define MTOT (B_*N_)   // 4096

// 1/sqrt(128) * log2(e): exp2-domain softmax (folded into Q projection scale)
#define QSC 0.12751743f

typedef __attribute__((ext_vector_type(8))) short bf16x8;  // 8 bf16 = 4 VGPRs
typedef __attribute__((ext_vector_type(4))) float f32x4;

__device__ __forceinline__ unsigned short f2bf(float f) {
  union { float f; uint32_t u; } a; a.f = f;
  uint32_t u = a.u;
  uint32_t r = (u + 0x7fffu + ((u >> 16) & 1u)) >> 16;  // RNE, inputs finite
  return (unsigned short)r;
}

// truncating bf16 pack of two positive floats (rel err <= 2^-8)
__device__ __forceinline__ uint32_t pack_bf2(float a, float b) {
  union { float f; uint32_t u; } x, y; x.f = a; y.f = b;
  return (x.u >> 16) | (y.u & 0xffff0000u);
}

// async global->LDS, 16B per lane. LDS dest must be wave-uniform base + lane*16.
__device__ __forceinline__ void g2l16(const void* g, void* l) {
  __builtin_amdgcn_global_load_lds(
      (__attribute__((address_space(1))) void*)(void*)(uintptr_t)g,
      (__attribute__((address_space(3))) void*)l,
      16, 0, 0);
}

// ---------------- fused fp32 -> bf16 cast of all 7 tensors ----------------
__global__ void cast_all(const float* __restrict__ q, const float* __restrict__ k,
                         const float* __restrict__ v, const float* __restrict__ wq,
                         const float* __restrict__ wk, const float* __restrict__ wv,
                         const float* __restrict__ wo, unsigned short* __restrict__ dst) {
  int i = blockIdx.x * 256 + threadIdx.x;  // float4 index, grid sized exactly
  const float* src; int base;
  if      (i < 2097152) { src = q;  base = 0; }
  else if (i < 4194304) { src = k;  base = 2097152; }
  else if (i < 6291456) { src = v;  base = 4194304; }
  else if (i < 7340032) { src = wq; base = 6291456; }
  else if (i < 7602176) { src = wk; base = 7340032; }
  else if (i < 7864320) { src = wv; base = 7602176; }
  else                  { src = wo; base = 7864320; }
  float4 val = ((const float4*)src)[i - base];
  ushort4 o;
  o.x = f2bf(val.x); o.y = f2bf(val.y); o.z = f2bf(val.z); o.w = f2bf(val.w);
  ((ushort4*)dst)[i] = o;
}

// ---------------- shared GEMM K-loop (m97 structure, BK=32) ----------------
__device__ __forceinline__ void gemm_kloop(const unsigned short* __restrict__ A,
                                           const unsigned short* __restrict__ W,
                                           unsigned short* As, unsigned short* Bs,
                                           int bm, int bn, int K,
                                           int wm, int wn, int tid, int l16, int quad,
                                           f32x4 acc[4][4]) {
  for (int k0 = 0; k0 < K; k0 += 32) {
    __syncthreads();
#pragma unroll
    for (int r = 0; r < 2; ++r) {
      int c = r * 256 + tid;
      int row = c >> 2, c8 = (c & 3) << 3;
      g2l16(A + (size_t)(bm + row) * K + k0 + c8, (char*)As + (size_t)c * 16);
    }
#pragma unroll
    for (int r = 0; r < 2; ++r) {
      int c = r * 256 + tid;
      int row = c >> 2, c8 = (c & 3) << 3;
      g2l16(W + (size_t)(bn + row) * K + k0 + c8, (char*)Bs + (size_t)c * 16);
    }
    __syncthreads();

    bf16x8 af[4], bf[4];
#pragma unroll
    for (int mi = 0; mi < 4; ++mi)
      af[mi] = *(const bf16x8*)(As + (wm + mi * 16 + l16) * 32 + quad * 8);
#pragma unroll
    for (int ni = 0; ni < 4; ++ni)
      bf[ni] = *(const bf16x8*)(Bs + (wn + ni * 16 + l16) * 32 + quad * 8);
#pragma unroll
    for (int mi = 0; mi < 4; ++mi)
#pragma unroll
      for (int ni = 0; ni < 4; ++ni)
        acc[mi][ni] = __builtin_amdgcn_mfma_f32_16x16x32_bf16(af[mi], bf[ni], acc[mi][ni], 0, 0, 0);
  }
}

// ---------------- fused Q/K/V projection ----------------
__global__ __launch_bounds__(256, 3)
void proj_fused(const unsigned short* __restrict__ qb, const unsigned short* __restrict__ kb,
                const unsigned short* __restrict__ vb,
                const unsigned short* __restrict__ Wqb, const unsigned short* __restrict__ Wkb,
                const unsigned short* __restrict__ Wvb,
                const float* __restrict__ bq, const float* __restrict__ bk,
                const float* __restrict__ bv,
                unsigned short* __restrict__ Qb, unsigned short* __restrict__ Kpp,
                unsigned short* __restrict__ Vtt) {
  __shared__ unsigned short As[128 * 32];
  __shared__ unsigned short Bs[128 * 32];
  const int tid  = threadIdx.x;
  const int wave = tid >> 6, lane = tid & 63;
  const int l16  = lane & 15, quad = lane >> 4;
  const int bm = blockIdx.x * 128;
  const int wm = (wave & 1) * 64, wn = (wave >> 1) * 64;
  const int y = blockIdx.y;

  const unsigned short *A, *W;
  const float* bias;
  unsigned short* out;
  int bn, mode, Nn;
  float scale;
  if (y < 16)      { A = qb; W = Wqb; bias = bq; out = Qb;  bn = y * 128;        mode = 0; Nn = 2048; scale = QSC;  }
  else if (y < 20) { A = kb; W = Wkb; bias = bk; out = Kpp; bn = (y - 16) * 128; mode = 0; Nn = 512;  scale = 1.0f; }
  else             { A = vb; W = Wvb; bias = bv; out = Vtt; bn = (y - 20) * 128; mode = 1; Nn = 512;  scale = 1.0f; }

  f32x4 acc[4][4] = {};
  gemm_kloop(A, W, As, Bs, bm, bn, E_, wm, wn, tid, l16, quad, acc);

  if (mode == 0) {
#pragma unroll
    for (int mi = 0; mi < 4; ++mi)
#pragma unroll
      for (int ni = 0; ni < 4; ++ni) {
        int col = bn + wn + ni * 16 + l16;
        float bb = bias[col];
        int row0 = bm + wm + mi * 16 + quad * 4;
#pragma unroll
        for (int r = 0; r < 4; ++r)
          out[(size_t)(row0 + r) * Nn + col] = f2bf((acc[mi][ni][r] + bb) * scale);
      }
  } else {  // V: transposed per batch -> Vt[(b*KVE + col)*N + s]
#pragma unroll
    for (int mi = 0; mi < 4; ++mi)
#pragma unroll
      for (int ni = 0; ni < 4; ++ni) {
        int col = bn + wn + ni * 16 + l16;
        float bb = bias[col];
        int row0 = bm + wm + mi * 16 + quad * 4;
        int b = row0 >> 11, s = row0 & 2047;
        ushort4 o;
        o.x = f2bf(acc[mi][ni][0] + bb);
        o.y = f2bf(acc[mi][ni][1] + bb);
        o.z = f2bf(acc[mi][ni][2] + bb);
        o.w = f2bf(acc[mi][ni][3] + bb);
        *(ushort4*)(out + (size_t)(b * KVE_ + col) * N_ + s) = o;
      }
  }
}

// ---------------- output projection (fp32 out) ----------------
__global__ __launch_bounds__(256, 2)
void gemm_out(const unsigned short* __restrict__ A, const unsigned short* __restrict__ W,
              const float* __restrict__ bias, float* __restrict__ Cout) {
  __shared__ unsigned short As[128 * 32];
  __shared__ unsigned short Bs[128 * 32];
  const int tid  = threadIdx.x;
  const int wave = tid >> 6, lane = tid & 63;
  const int l16  = lane & 15, quad = lane >> 4;
  const int bm = blockIdx.x * 128, bn = blockIdx.y * 128;
  const int wm = (wave & 1) * 64, wn = (wave >> 1) * 64;

  f32x4 acc[4][4] = {};
  gemm_kloop(A, W, As, Bs, bm, bn, E_, wm, wn, tid, l16, quad, acc);

#pragma unroll
  for (int mi = 0; mi < 4; ++mi)
#pragma unroll
    for (int ni = 0; ni < 4; ++ni) {
      int col = bn + wn + ni * 16 + l16;
      float bb = bias[col];
      int row0 = bm + wm + mi * 16 + quad * 4;
#pragma unroll
      for (int r = 0; r < 4; ++r)
        Cout[(size_t)(row0 + r) * E_ + col] = acc[mi][ni][r] + bb;
    }
}

// ---------------- Flash attention, transposed-S GQA, no-running-max ----------------
// R2: LDS-traffic attack. R0=R1=82us showed DS pipe ~60%+ busy was the wall:
// R1's mi=1 tile costs 1.0 ds_read/MFMA and 4x K-frag duplication across waves.
// This version restores the 2x2 wave grid (qg owns 32 q rows -> mi=2 = 0.5
// reads/MFMA, kf duplication 2x), keeps 64-key tiles, and drops V from LDS
// entirely: V^T slice (512 KB per (b,hk)) is L2-resident (x-fastest dispatch
// keeps same-bh blocks adjacent), so vf is 8 direct global dwordx4 loads
// issued right after QK so softmax covers the L2 latency.
// LDS = 2x16KB K double-buffer (+1KB Xt) -> 4 blocks/CU by LDS;
// launch_bounds(256,3) caps VGPR at 170 (o+qf+vf peak ~165; a 128 cap spills).
// Grid (32,32): one 64-row q-tile per block, reflection map balances per-CU
// causal work (sums 62 under round-robin).
__global__ __launch_bounds__(256, 3)
void attn_gqa(const unsigned short* __restrict__ Qp,
              const unsigned short* __restrict__ Kp,
              const unsigned short* __restrict__ Vt,
              unsigned short* __restrict__ Ob,
              const int* __restrict__ is_causal_p) {
  __shared__ unsigned short lds[2][8192];  // 2 x 16KB K tiles = 32 KB
  __shared__ float Xt[256];                // sg=1 tsum partials

  const int tid  = threadIdx.x;
  const int wave = tid >> 6, lane = tid & 63;
  const int l16  = lane & 15, quad = lane >> 4;
  const int qg = wave >> 1, sg = wave & 1;
  const int bh = blockIdx.y;
  const int u  = (blockIdx.x + bh) & 31;
  const int qt = (u < 16) ? u : 47 - u;   // 64-row q-tile; balanced per-CU sum
  const int b = bh >> 4, hq = bh & 15, hk = hq >> 2;
  const int causal = *is_causal_p;

  const unsigned short* Kbase = Kp + (size_t)b * N_ * KVE_ + hk * D_;
  const unsigned short* Vbase = Vt + (size_t)(b * KVE_ + hk * D_) * N_;

  const int nt = causal ? qt + 1 : (N_ / 64);  // 64-key tiles
  const int qw = qt * 64 + qg * 32;            // wave's 32-q window start

  // K staging, fragment-major: block (sblk,kk) at shorts ((sblk*4+kk)*64+lane)*8
  // (lane reads K[s=sblk*16+l16][d=kk*32+quad*8..+7] -> A-operand).
  auto stage = [&](int t, int buf) {
    int s0 = t * 64;
    unsigned short* Kd = &lds[buf][0];
#pragma unroll
    for (int r = 0; r < 4; ++r) {
      int idx = r * 256 + tid;
      int s = (idx >> 8) * 16 + (idx & 15);
      int d = ((idx >> 6) & 3) * 32 + ((idx >> 4) & 3) * 8;
      g2l16(Kbase + (size_t)(s0 + s) * KVE_ + d, Kd + (size_t)idx * 8);
    }
  };

  // Q fragments (B-operand: n=l16 -> q, k=quad*8+j -> d), exp2-scaled already
  bf16x8 qf[2][4];
#pragma unroll
  for (int mi = 0; mi < 2; ++mi)
#pragma unroll
    for (int kk = 0; kk < 4; ++kk)
      qf[mi][kk] = *(const bf16x8*)(Qp + (size_t)(b * N_ + qw + mi * 16 + l16) * E_ +
                                    hq * D_ + kk * 32 + quad * 8);

  f32x4 o[2][8] = {};
  float tsum[2] = { 0.f, 0.f };  // per-lane l partials (this wave's s rows)

  stage(0, 0);
  __syncthreads();

  for (int t = 0; t < nt; ++t) {
    if (t + 1 < nt) stage(t + 1, (t + 1) & 1);  // overlaps compute(t)
    const unsigned short* Kb = &lds[t & 1][0];
    const int sw = t * 64 + sg * 32;  // wave's 32-s window start
    const bool active = !causal || (sw <= qw + 31);  // wave-uniform

    if (active) {
      // S^T = K Q^T : rows s = sw + ni*16+quad*4+r, cols q = qw + mi*16+l16
      f32x4 sa[2][2] = {};
#pragma unroll
      for (int kk = 0; kk < 4; ++kk) {
        bf16x8 kf[2];
#pragma unroll
        for (int ni = 0; ni < 2; ++ni)
          kf[ni] = *(const bf16x8*)(Kb + (((sg * 2 + ni) * 4 + kk) * 64 + lane) * 8);
#pragma unroll
        for (int mi = 0; mi < 2; ++mi)
#pragma unroll
          for (int ni = 0; ni < 2; ++ni)
            sa[mi][ni] = __builtin_amdgcn_mfma_f32_16x16x32_bf16(kf[ni], qf[mi][kk], sa[mi][ni], 0, 0, 0);
      }

      // V direct from global (L2-resident): issue early so softmax covers latency.
      // lane reads V^T[d=n8*16+l16][s=sw+quad*8..+7] -> A-operand.
      bf16x8 vf[8];
#pragma unroll
      for (int n8 = 0; n8 < 8; ++n8)
        vf[n8] = *(const bf16x8*)(Vbase + (size_t)(n8 * 16 + l16) * N_ + sw + quad * 8);

      if (causal && sw + 31 > qw) {  // diagonal overlap: mask s > q
#pragma unroll
        for (int mi = 0; mi < 2; ++mi)
#pragma unroll
          for (int ni = 0; ni < 2; ++ni) {
            int sbase = sw + ni * 16 + quad * 4;
            int q = qw + mi * 16 + l16;
#pragma unroll
            for (int r = 0; r < 4; ++r)
              if (sbase + r > q) sa[mi][ni][r] = -3.0e38f;
          }
      }

      // P = exp2(S) (no max subtraction), pack to bf16 pairs in-register
      uint32_t pk[2][2][2];
#pragma unroll
      for (int mi = 0; mi < 2; ++mi)
#pragma unroll
        for (int ni = 0; ni < 2; ++ni) {
#pragma unroll
          for (int r = 0; r < 4; ++r) {
            float e = __builtin_amdgcn_exp2f(sa[mi][ni][r]);
            tsum[mi] += e;
            sa[mi][ni][r] = e;
          }
          pk[mi][ni][0] = pack_bf2(sa[mi][ni][0], sa[mi][ni][1]);
          pk[mi][ni][1] = pack_bf2(sa[mi][ni][2], sa[mi][ni][3]);
        }

      // O^T += V^T[:, sw:sw+32] P^T[sw:sw+32, :]; B-operand P via shuffle net.
#pragma unroll
      for (int mi = 0; mi < 2; ++mi) {
        union { bf16x8 v; uint32_t w[4]; } pb;
#pragma unroll
        for (int h = 0; h < 4; ++h) {
          int src = ((quad & 1) * 2 + (h >> 1)) * 16 + l16;
          uint32_t v0 = __shfl(pk[mi][0][h & 1], src);
          uint32_t v1 = __shfl(pk[mi][1][h & 1], src);
          pb.w[h] = (quad & 2) ? v1 : v0;
        }
#pragma unroll
        for (int n8 = 0; n8 < 8; ++n8)
          o[mi][n8] = __builtin_amdgcn_mfma_f32_16x16x32_bf16(vf[n8], pb.v, o[mi][n8], 0, 0, 0);
      }
    }
    __syncthreads();  // drains stage(t+1); protects K-buffer reuse
  }

  // ---- combine sg partials via LDS (K buffers are spent), epilogue ----
  float4* X4 = (float4*)&lds[0][0];  // 2048 float4 = 32 KB (both K buffers)
  if (sg == 1) {
#pragma unroll
    for (int mi = 0; mi < 2; ++mi) {
#pragma unroll
      for (int ni = 0; ni < 8; ++ni) {
        float4 w;
        w.x = o[mi][ni][0]; w.y = o[mi][ni][1]; w.z = o[mi][ni][2]; w.w = o[mi][ni][3];
        X4[((qg * 2 + mi) * 8 + ni) * 64 + lane] = w;
      }
      Xt[(qg * 2 + mi) * 64 + lane] = tsum[mi];
    }
  }
  __syncthreads();
  if (sg == 0) {
#pragma unroll
    for (int mi = 0; mi < 2; ++mi) {
      float lt = tsum[mi] + Xt[(qg * 2 + mi) * 64 + lane];
      lt += __shfl_xor(lt, 16);
      lt += __shfl_xor(lt, 32);
      float inv = 1.0f / lt;
      int q = qw + mi * 16 + l16;
#pragma unroll
      for (int ni = 0; ni < 8; ++ni) {
        float4 xx = X4[((qg * 2 + mi) * 8 + ni) * 64 + lane];
        ushort4 st;
        st.x = f2bf((o[mi][ni][0] + xx.x) * inv);
        st.y = f2bf((o[mi][ni][1] + xx.y) * inv);
        st.z = f2bf((o[mi][ni][2] + xx.z) * inv);
        st.w = f2bf((o[mi][ni][3] + xx.w) * inv);
        *(ushort4*)(Ob + (size_t)(b * N_ + q) * E_ + hq * D_ + ni * 16 + quad * 4) = st;
      }
    }
  }
}

// ---------------- host ----------------
extern "C" void kernel_launch(void* const* d_in, const int* in_sizes, int n_in,
                              void* d_out, int out_size, void* d_ws, size_t ws_size,
                              hipStream_t stream) {
  const float* query = (const float*)d_in[0];
  const float* key   = (const float*)d_in[1];
  const float* value = (const float*)d_in[2];
  const float* Wq = (const float*)d_in[3];
  const float* bq = (const float*)d_in[4];
  const float* Wk = (const float*)d_in[5];
  const float* bk = (const float*)d_in[6];
  const float* Wv = (const float*)d_in[7];
  const float* bv = (const float*)d_in[8];
  const float* Wo = (const float*)d_in[9];
  const float* bo = (const float*)d_in[10];
  const int* is_causal = (const int*)d_in[11];

  char* ws = (char*)d_ws;
  size_t off = 0;
  auto alloc = [&](size_t bytes) {
    char* p = ws + off;
    off += (bytes + 255) & ~(size_t)255;
    return p;
  };
  // NOTE: qb..Wob must stay contiguous in this order (cast_all writes one region)
  unsigned short* qb  = (unsigned short*)alloc((size_t)MTOT * E_ * 2);
  unsigned short* kb  = (unsigned short*)alloc((size_t)MTOT * E_ * 2);
  unsigned short* vb  = (unsigned short*)alloc((size_t)MTOT * E_ * 2);
  unsigned short* Wqb = (unsigned short*)alloc((size_t)E_ * E_ * 2);
  unsigned short* Wkb = (unsigned short*)alloc((size_t)KVE_ * E_ * 2);
  unsigned short* Wvb = (unsigned short*)alloc((size_t)KVE_ * E_ * 2);
  unsigned short* Wob = (unsigned short*)alloc((size_t)E_ * E_ * 2);
  unsigned short* Qb  = (unsigned short*)alloc((size_t)MTOT * E_ * 2);
  unsigned short* Kpp = (unsigned short*)alloc((size_t)MTOT * KVE_ * 2);
  unsigned short* Vtt = (unsigned short*)alloc((size_t)MTOT * KVE_ * 2);
  unsigned short* Ob  = (unsigned short*)alloc((size_t)MTOT * E_ * 2);
  (void)ws_size; (void)n_in; (void)in_sizes; (void)out_size;

  dim3 blk(256);
  cast_all<<<dim3(34816), blk, 0, stream>>>(query, key, value, Wq, Wk, Wv, Wo, qb);
  proj_fused<<<dim3(32, 24), blk, 0, stream>>>(qb, kb, vb, Wqb, Wkb, Wvb,
                                               bq, bk, bv, Qb, Kpp, Vtt);
  attn_gqa<<<dim3(32, 32), blk, 0, stream>>>(Qb, Kpp, Vtt, Ob, is_causal);
  gemm_out<<<dim3(32, 16), blk, 0, stream>>>(Ob, Wob, bo, (float*)d_out);
}

// Round 3
// 393.606 us; speedup vs baseline: 1.1109x; 1.1109x over previous
//
#include <hip/hip_runtime.h>
#include <stdint.h>

#define E_   2048
#define HQ_  16
#define HK_  4
#define D_   128
#define G_   4
#define KVE_ 512
#define B_   2
#define N_   2048
#define MTOT (B_*N_)   // 4096

// 1/sqrt(128) * log2(e): exp2-domain softmax (folded into Q projection scale)
#define QSC 0.12751743f

typedef __attribute__((ext_vector_type(8))) short bf16x8;  // 8 bf16 = 4 VGPRs
typedef __attribute__((ext_vector_type(4))) float f32x4;

__device__ __forceinline__ unsigned short f2bf(float f) {
  union { float f; uint32_t u; } a; a.f = f;
  uint32_t u = a.u;
  uint32_t r = (u + 0x7fffu + ((u >> 16) & 1u)) >> 16;  // RNE, inputs finite
  return (unsigned short)r;
}

// truncating bf16 pack of two positive floats (rel err <= 2^-8)
__device__ __forceinline__ uint32_t pack_bf2(float a, float b) {
  union { float f; uint32_t u; } x, y; x.f = a; y.f = b;
  return (x.u >> 16) | (y.u & 0xffff0000u);
}

// async global->LDS, 16B per lane. LDS dest must be wave-uniform base + lane*16.
__device__ __forceinline__ void g2l16(const void* g, void* l) {
  __builtin_amdgcn_global_load_lds(
      (__attribute__((address_space(1))) void*)(void*)(uintptr_t)g,
      (__attribute__((address_space(3))) void*)l,
      16, 0, 0);
}

// ---------------- fused fp32 -> bf16 cast of all 7 tensors ----------------
__global__ void cast_all(const float* __restrict__ q, const float* __restrict__ k,
                         const float* __restrict__ v, const float* __restrict__ wq,
                         const float* __restrict__ wk, const float* __restrict__ wv,
                         const float* __restrict__ wo, unsigned short* __restrict__ dst) {
  int i = blockIdx.x * 256 + threadIdx.x;  // float4 index, grid sized exactly
  const float* src; int base;
  if      (i < 2097152) { src = q;  base = 0; }
  else if (i < 4194304) { src = k;  base = 2097152; }
  else if (i < 6291456) { src = v;  base = 4194304; }
  else if (i < 7340032) { src = wq; base = 6291456; }
  else if (i < 7602176) { src = wk; base = 7340032; }
  else if (i < 7864320) { src = wv; base = 7602176; }
  else                  { src = wo; base = 7864320; }
  float4 val = ((const float4*)src)[i - base];
  ushort4 o;
  o.x = f2bf(val.x); o.y = f2bf(val.y); o.z = f2bf(val.z); o.w = f2bf(val.w);
  ((ushort4*)dst)[i] = o;
}

// ---------------- shared GEMM K-loop (m97 structure, BK=64, XOR-swizzled LDS) ----
// BK 32->64 halves the per-iter barrier/vmcnt(0) drain count (the dominant
// structural stall of this 2-barrier template at these sizes). The [128][64]
// row (128 B) would put all 16 l16-lanes of a fragment read in one bank, so
// 16B slots are XOR-swizzled by (row&7) on BOTH sides (pre-swizzled global
// source slot on stage + same XOR on the ds_read col slot) -> 2 lanes/bank.
__device__ __forceinline__ void gemm_kloop(const unsigned short* __restrict__ A,
                                           const unsigned short* __restrict__ W,
                                           unsigned short* As, unsigned short* Bs,
                                           int bm, int bn, int K,
                                           int wm, int wn, int tid, int l16, int quad,
                                           f32x4 acc[4][4]) {
  const int swz = l16 & 7;  // (row & 7) for fragment rows wm+mi*16+l16
  for (int k0 = 0; k0 < K; k0 += 64) {
    __syncthreads();
#pragma unroll
    for (int r = 0; r < 4; ++r) {
      int c = r * 256 + tid;
      int row = c >> 3;
      int gs = ((c & 7) ^ (row & 7)) << 3;
      g2l16(A + (size_t)(bm + row) * K + k0 + gs, (char*)As + (size_t)c * 16);
    }
#pragma unroll
    for (int r = 0; r < 4; ++r) {
      int c = r * 256 + tid;
      int row = c >> 3;
      int gs = ((c & 7) ^ (row & 7)) << 3;
      g2l16(W + (size_t)(bn + row) * K + k0 + gs, (char*)Bs + (size_t)c * 16);
    }
    __syncthreads();

#pragma unroll
    for (int kk = 0; kk < 2; ++kk) {
      bf16x8 af[4], bf[4];
#pragma unroll
      for (int mi = 0; mi < 4; ++mi)
        af[mi] = *(const bf16x8*)(As + (size_t)(wm + mi * 16 + l16) * 64 +
                                  ((((kk << 2) | quad) ^ swz) << 3));
#pragma unroll
      for (int ni = 0; ni < 4; ++ni)
        bf[ni] = *(const bf16x8*)(Bs + (size_t)(wn + ni * 16 + l16) * 64 +
                                  ((((kk << 2) | quad) ^ swz) << 3));
#pragma unroll
      for (int mi = 0; mi < 4; ++mi)
#pragma unroll
        for (int ni = 0; ni < 4; ++ni)
          acc[mi][ni] = __builtin_amdgcn_mfma_f32_16x16x32_bf16(af[mi], bf[ni], acc[mi][ni], 0, 0, 0);
    }
  }
}

// ---------------- fused Q/K/V projection ----------------
__global__ __launch_bounds__(256, 3)
void proj_fused(const unsigned short* __restrict__ qb, const unsigned short* __restrict__ kb,
                const unsigned short* __restrict__ vb,
                const unsigned short* __restrict__ Wqb, const unsigned short* __restrict__ Wkb,
                const unsigned short* __restrict__ Wvb,
                const float* __restrict__ bq, const float* __restrict__ bk,
                const float* __restrict__ bv,
                unsigned short* __restrict__ Qb, unsigned short* __restrict__ Kpp,
                unsigned short* __restrict__ Vtt) {
  __shared__ unsigned short As[128 * 64];
  __shared__ unsigned short Bs[128 * 64];
  const int tid  = threadIdx.x;
  const int wave = tid >> 6, lane = tid & 63;
  const int l16  = lane & 15, quad = lane >> 4;
  const int bm = blockIdx.x * 128;
  const int wm = (wave & 1) * 64, wn = (wave >> 1) * 64;
  const int y = blockIdx.y;

  const unsigned short *A, *W;
  const float* bias;
  unsigned short* out;
  int bn, mode, Nn;
  float scale;
  if (y < 16)      { A = qb; W = Wqb; bias = bq; out = Qb;  bn = y * 128;        mode = 0; Nn = 2048; scale = QSC;  }
  else if (y < 20) { A = kb; W = Wkb; bias = bk; out = Kpp; bn = (y - 16) * 128; mode = 0; Nn = 512;  scale = 1.0f; }
  else             { A = vb; W = Wvb; bias = bv; out = Vtt; bn = (y - 20) * 128; mode = 1; Nn = 512;  scale = 1.0f; }

  f32x4 acc[4][4] = {};
  gemm_kloop(A, W, As, Bs, bm, bn, E_, wm, wn, tid, l16, quad, acc);

  if (mode == 0) {
#pragma unroll
    for (int mi = 0; mi < 4; ++mi)
#pragma unroll
      for (int ni = 0; ni < 4; ++ni) {
        int col = bn + wn + ni * 16 + l16;
        float bb = bias[col];
        int row0 = bm + wm + mi * 16 + quad * 4;
#pragma unroll
        for (int r = 0; r < 4; ++r)
          out[(size_t)(row0 + r) * Nn + col] = f2bf((acc[mi][ni][r] + bb) * scale);
      }
  } else {  // V: transposed per batch -> Vt[(b*KVE + col)*N + s]
#pragma unroll
    for (int mi = 0; mi < 4; ++mi)
#pragma unroll
      for (int ni = 0; ni < 4; ++ni) {
        int col = bn + wn + ni * 16 + l16;
        float bb = bias[col];
        int row0 = bm + wm + mi * 16 + quad * 4;
        int b = row0 >> 11, s = row0 & 2047;
        ushort4 o;
        o.x = f2bf(acc[mi][ni][0] + bb);
        o.y = f2bf(acc[mi][ni][1] + bb);
        o.z = f2bf(acc[mi][ni][2] + bb);
        o.w = f2bf(acc[mi][ni][3] + bb);
        *(ushort4*)(out + (size_t)(b * KVE_ + col) * N_ + s) = o;
      }
  }
}

// ---------------- output projection (fp32 out) ----------------
__global__ __launch_bounds__(256, 2)
void gemm_out(const unsigned short* __restrict__ A, const unsigned short* __restrict__ W,
              const float* __restrict__ bias, float* __restrict__ Cout) {
  __shared__ unsigned short As[128 * 64];
  __shared__ unsigned short Bs[128 * 64];
  const int tid  = threadIdx.x;
  const int wave = tid >> 6, lane = tid & 63;
  const int l16  = lane & 15, quad = lane >> 4;
  const int bm = blockIdx.x * 128, bn = blockIdx.y * 128;
  const int wm = (wave & 1) * 64, wn = (wave >> 1) * 64;

  f32x4 acc[4][4] = {};
  gemm_kloop(A, W, As, Bs, bm, bn, E_, wm, wn, tid, l16, quad, acc);

#pragma unroll
  for (int mi = 0; mi < 4; ++mi)
#pragma unroll
    for (int ni = 0; ni < 4; ++ni) {
      int col = bn + wn + ni * 16 + l16;
      float bb = bias[col];
      int row0 = bm + wm + mi * 16 + quad * 4;
#pragma unroll
      for (int r = 0; r < 4; ++r)
        Cout[(size_t)(row0 + r) * E_ + col] = acc[mi][ni][r] + bb;
    }
}

// ---------------- Flash attention, transposed-S GQA, no-running-max ----------------
// R3: R0's proven 2x2 wave structure (qg owns 32 q rows, sg owns 32 of 64
// keys; 0.5 ds_read/MFMA) with K double-buffered (32 KB) and V SINGLE-
// buffered (16 KB) -> 49 KB LDS -> 3 blocks/CU (was 2). Grid (32,32): one
// 64-row q-tile per block (reflection map balances causal work). V single-
// buffering costs a second barrier per tile: vf is read into registers AFTER
// pk is packed (sa dead -> peak regs ~150, under the (256,3) cap of 168; R2's
// spill came from vf+sa co-live at cap 168), then B1 allows stage(t+1) to
// overwrite Vlds while shuffles+PV cover the load latency; B2 drains.
__global__ __launch_bounds__(256, 3)
void attn_gqa(const unsigned short* __restrict__ Qp,
              const unsigned short* __restrict__ Kp,
              const unsigned short* __restrict__ Vt,
              unsigned short* __restrict__ Ob,
              const int* __restrict__ is_causal_p) {
  __shared__ unsigned short Klds[2][8192];  // 2 x 16 KB K tiles (double buffer)
  __shared__ unsigned short Vlds[8192];     // 16 KB V tile (single buffer)
  __shared__ float Xt[256];                 // sg=1 tsum partials

  const int tid  = threadIdx.x;
  const int wave = tid >> 6, lane = tid & 63;
  const int l16  = lane & 15, quad = lane >> 4;
  const int qg = wave >> 1, sg = wave & 1;
  const int bh = blockIdx.y;
  const int u  = (blockIdx.x + bh) & 31;
  const int qt = (u < 16) ? u : 47 - u;   // 64-row q-tile; balanced per-CU sum
  const int b = bh >> 4, hq = bh & 15, hk = hq >> 2;
  const int causal = *is_causal_p;

  const unsigned short* Kbase = Kp + (size_t)b * N_ * KVE_ + hk * D_;
  const unsigned short* Vbase = Vt + (size_t)(b * KVE_ + hk * D_) * N_;

  const int nt = causal ? qt + 1 : (N_ / 64);  // 64-key tiles
  const int qw = qt * 64 + qg * 32;            // wave's 32-q window start

  // K staging, fragment-major: block (sblk,kk) at shorts ((sblk*4+kk)*64+lane)*8
  // (lane reads K[s=sblk*16+l16][d=kk*32+quad*8..+7] -> A-operand).
  auto stageK = [&](int t, int buf) {
    int s0 = t * 64;
    unsigned short* Kd = &Klds[buf][0];
#pragma unroll
    for (int r = 0; r < 4; ++r) {
      int idx = r * 256 + tid;
      int s = (idx >> 8) * 16 + (idx & 15);
      int d = ((idx >> 6) & 3) * 32 + ((idx >> 4) & 3) * 8;
      g2l16(Kbase + (size_t)(s0 + s) * KVE_ + d, Kd + (size_t)idx * 8);
    }
  };
  // V staging: block (dblk,kkv) at shorts ((dblk*2+kkv)*64+lane)*8
  // (lane reads V^T[d=dblk*16+l16][s=kkv*32+quad*8..+7] -> A-operand).
  auto stageV = [&](int t) {
    int s0 = t * 64;
#pragma unroll
    for (int r = 0; r < 4; ++r) {
      int idx = r * 256 + tid;
      int d = (idx >> 7) * 16 + (idx & 15);
      int sc = ((idx >> 6) & 1) * 32 + ((idx >> 4) & 3) * 8;
      g2l16(Vbase + (size_t)d * N_ + s0 + sc, Vlds + (size_t)idx * 8);
    }
  };

  // Q fragments (B-operand: n=l16 -> q, k=quad*8+j -> d), exp2-scaled already
  bf16x8 qf[2][4];
#pragma unroll
  for (int mi = 0; mi < 2; ++mi)
#pragma unroll
    for (int kk = 0; kk < 4; ++kk)
      qf[mi][kk] = *(const bf16x8*)(Qp + (size_t)(b * N_ + qw + mi * 16 + l16) * E_ +
                                    hq * D_ + kk * 32 + quad * 8);

  f32x4 o[2][8] = {};
  float tsum[2] = { 0.f, 0.f };  // per-lane l partials (this wave's s rows)

  stageK(0, 0);
  stageV(0);
  __syncthreads();

  for (int t = 0; t < nt; ++t) {
    const unsigned short* Kb = &Klds[t & 1][0];
    const int sw = t * 64 + sg * 32;  // wave's 32-s window start
    const bool active = !causal || (sw <= qw + 31);  // wave-uniform

    uint32_t pk[2][2][2];
    bf16x8 vf[8];
    if (active) {
      // S^T = K Q^T : rows s = sw + ni*16+quad*4+r, cols q = qw + mi*16+l16
      f32x4 sa[2][2] = {};
#pragma unroll
      for (int kk = 0; kk < 4; ++kk) {
        bf16x8 kf[2];
#pragma unroll
        for (int ni = 0; ni < 2; ++ni)
          kf[ni] = *(const bf16x8*)(Kb + (((sg * 2 + ni) * 4 + kk) * 64 + lane) * 8);
#pragma unroll
        for (int mi = 0; mi < 2; ++mi)
#pragma unroll
          for (int ni = 0; ni < 2; ++ni)
            sa[mi][ni] = __builtin_amdgcn_mfma_f32_16x16x32_bf16(kf[ni], qf[mi][kk], sa[mi][ni], 0, 0, 0);
      }

      if (causal && sw + 31 > qw) {  // diagonal overlap: mask s > q
#pragma unroll
        for (int mi = 0; mi < 2; ++mi)
#pragma unroll
          for (int ni = 0; ni < 2; ++ni) {
            int sbase = sw + ni * 16 + quad * 4;
            int q = qw + mi * 16 + l16;
#pragma unroll
            for (int r = 0; r < 4; ++r)
              if (sbase + r > q) sa[mi][ni][r] = -3.0e38f;
          }
      }

      // P = exp2(S) (no max subtraction), pack to bf16 pairs in-register
#pragma unroll
      for (int mi = 0; mi < 2; ++mi)
#pragma unroll
        for (int ni = 0; ni < 2; ++ni) {
#pragma unroll
          for (int r = 0; r < 4; ++r) {
            float e = __builtin_amdgcn_exp2f(sa[mi][ni][r]);
            tsum[mi] += e;
            sa[mi][ni][r] = e;
          }
          pk[mi][ni][0] = pack_bf2(sa[mi][ni][0], sa[mi][ni][1]);
          pk[mi][ni][1] = pack_bf2(sa[mi][ni][2], sa[mi][ni][3]);
        }

      // vf AFTER pk (sa dead) to keep peak registers under the 168 cap;
      // sched_barrier stops the scheduler hoisting these into the sa region.
      __builtin_amdgcn_sched_barrier(0);
#pragma unroll
      for (int n8 = 0; n8 < 8; ++n8)
        vf[n8] = *(const bf16x8*)(Vlds + ((n8 * 2 + sg) * 64 + lane) * 8);
    }

    __syncthreads();  // B1: all waves' Vlds (and Klds[t&1]) reads complete

    if (t + 1 < nt) {           // stage next tile; latency covered by shfl+PV
      stageK(t + 1, (t + 1) & 1);
      stageV(t + 1);
    }

    if (active) {
      // O^T += V^T[:, sw:sw+32] P^T[sw:sw+32, :]; B-operand P via shuffle net.
#pragma unroll
      for (int mi = 0; mi < 2; ++mi) {
        union { bf16x8 v; uint32_t w[4]; } pb;
#pragma unroll
        for (int h = 0; h < 4; ++h) {
          int src = ((quad & 1) * 2 + (h >> 1)) * 16 + l16;
          uint32_t v0 = __shfl(pk[mi][0][h & 1], src);
          uint32_t v1 = __shfl(pk[mi][1][h & 1], src);
          pb.w[h] = (quad & 2) ? v1 : v0;
        }
#pragma unroll
        for (int n8 = 0; n8 < 8; ++n8)
          o[mi][n8] = __builtin_amdgcn_mfma_f32_16x16x32_bf16(vf[n8], pb.v, o[mi][n8], 0, 0, 0);
      }
    }

    __syncthreads();  // B2: drains stage(t+1) vmcnt; buffers ready for t+1
  }

  // ---- combine sg partials via LDS (K buffers are spent), epilogue ----
  float4* X4 = (float4*)&Klds[0][0];  // 2048 float4 = 32 KB (both K buffers)
  if (sg == 1) {
#pragma unroll
    for (int mi = 0; mi < 2; ++mi) {
#pragma unroll
      for (int ni = 0; ni < 8; ++ni) {
        float4 w;
        w.x = o[mi][ni][0]; w.y = o[mi][ni][1]; w.z = o[mi][ni][2]; w.w = o[mi][ni][3];
        X4[((qg * 2 + mi) * 8 + ni) * 64 + lane] = w;
      }
      Xt[(qg * 2 + mi) * 64 + lane] = tsum[mi];
    }
  }
  __syncthreads();
  if (sg == 0) {
#pragma unroll
    for (int mi = 0; mi < 2; ++mi) {
      float lt = tsum[mi] + Xt[(qg * 2 + mi) * 64 + lane];
      lt += __shfl_xor(lt, 16);
      lt += __shfl_xor(lt, 32);
      float inv = 1.0f / lt;
      int q = qw + mi * 16 + l16;
#pragma unroll
      for (int ni = 0; ni < 8; ++ni) {
        float4 xx = X4[((qg * 2 + mi) * 8 + ni) * 64 + lane];
        ushort4 st;
        st.x = f2bf((o[mi][ni][0] + xx.x) * inv);
        st.y = f2bf((o[mi][ni][1] + xx.y) * inv);
        st.z = f2bf((o[mi][ni][2] + xx.z) * inv);
        st.w = f2bf((o[mi][ni][3] + xx.w) * inv);
        *(ushort4*)(Ob + (size_t)(b * N_ + q) * E_ + hq * D_ + ni * 16 + quad * 4) = st;
      }
    }
  }
}

// ---------------- host ----------------
extern "C" void kernel_launch(void* const* d_in, const int* in_sizes, int n_in,
                              void* d_out, int out_size, void* d_ws, size_t ws_size,
                              hipStream_t stream) {
  const float* query = (const float*)d_in[0];
  const float* key   = (const float*)d_in[1];
  const float* value = (const float*)d_in[2];
  const float* Wq = (const float*)d_in[3];
  const float* bq = (const float*)d_in[4];
  const float* Wk = (const float*)d_in[5];
  const float* bk = (const float*)d_in[6];
  const float* Wv = (const float*)d_in[7];
  const float* bv = (const float*)d_in[8];
  const float* Wo = (const float*)d_in[9];
  const float* bo = (const float*)d_in[10];
  const int* is_causal = (const int*)d_in[11];

  char* ws = (char*)d_ws;
  size_t off = 0;
  auto alloc = [&](size_t bytes) {
    char* p = ws + off;
    off += (bytes + 255) & ~(size_t)255;
    return p;
  };
  // NOTE: qb..Wob must stay contiguous in this order (cast_all writes one region)
  unsigned short* qb  = (unsigned short*)alloc((size_t)MTOT * E_ * 2);
  unsigned short* kb  = (unsigned short*)alloc((size_t)MTOT * E_ * 2);
  unsigned short* vb  = (unsigned short*)alloc((size_t)MTOT * E_ * 2);
  unsigned short* Wqb = (unsigned short*)alloc((size_t)E_ * E_ * 2);
  unsigned short* Wkb = (unsigned short*)alloc((size_t)KVE_ * E_ * 2);
  unsigned short* Wvb = (unsigned short*)alloc((size_t)KVE_ * E_ * 2);
  unsigned short* Wob = (unsigned short*)alloc((size_t)E_ * E_ * 2);
  unsigned short* Qb  = (unsigned short*)alloc((size_t)MTOT * E_ * 2);
  unsigned short* Kpp = (unsigned short*)alloc((size_t)MTOT * KVE_ * 2);
  unsigned short* Vtt = (unsigned short*)alloc((size_t)MTOT * KVE_ * 2);
  unsigned short* Ob  = (unsigned short*)alloc((size_t)MTOT * E_ * 2);
  (void)ws_size; (void)n_in; (void)in_sizes; (void)out_size;

  dim3 blk(256);
  cast_all<<<dim3(34816), blk, 0, stream>>>(query, key, value, Wq, Wk, Wv, Wo, qb);
  proj_fused<<<dim3(32, 24), blk, 0, stream>>>(qb, kb, vb, Wqb, Wkb, Wvb,
                                               bq, bk, bv, Qb, Kpp, Vtt);
  attn_gqa<<<dim3(32, 32), blk, 0, stream>>>(Qb, Kpp, Vtt, Ob, is_causal);
  gemm_out<<<dim3(32, 16), blk, 0, stream>>>(Ob, Wob, bo, (float*)d_out);
}

// Round 4
// 356.047 us; speedup vs baseline: 1.2281x; 1.1055x over previous
//
#include <hip/hip_runtime.h>
#include <stdint.h>

#define E_   2048
#define HQ_  16
#define HK_  4
#define D_   128
#define G_   4
#define KVE_ 512
#define B_   2
#define N_   2048
#define MTOT (B_*N_)   // 4096

// 1/sqrt(128) * log2(e): exp2-domain softmax (folded into Q projection scale)
#define QSC 0.12751743f

typedef __attribute__((ext_vector_type(8))) short bf16x8;  // 8 bf16 = 4 VGPRs
typedef __attribute__((ext_vector_type(4))) float f32x4;

__device__ __forceinline__ unsigned short f2bf(float f) {
  union { float f; uint32_t u; } a; a.f = f;
  uint32_t u = a.u;
  uint32_t r = (u + 0x7fffu + ((u >> 16) & 1u)) >> 16;  // RNE, inputs finite
  return (unsigned short)r;
}

// truncating bf16 pack of two positive floats (rel err <= 2^-8)
__device__ __forceinline__ uint32_t pack_bf2(float a, float b) {
  union { float f; uint32_t u; } x, y; x.f = a; y.f = b;
  return (x.u >> 16) | (y.u & 0xffff0000u);
}

// async global->LDS, 16B per lane. LDS dest must be wave-uniform base + lane*16.
__device__ __forceinline__ void g2l16(const void* g, void* l) {
  __builtin_amdgcn_global_load_lds(
      (__attribute__((address_space(1))) void*)(void*)(uintptr_t)g,
      (__attribute__((address_space(3))) void*)l,
      16, 0, 0);
}

// ---------------- fused fp32 -> bf16 cast of all 7 tensors ----------------
__global__ void cast_all(const float* __restrict__ q, const float* __restrict__ k,
                         const float* __restrict__ v, const float* __restrict__ wq,
                         const float* __restrict__ wk, const float* __restrict__ wv,
                         const float* __restrict__ wo, unsigned short* __restrict__ dst) {
  int i = blockIdx.x * 256 + threadIdx.x;  // float4 index, grid sized exactly
  const float* src; int base;
  if      (i < 2097152) { src = q;  base = 0; }
  else if (i < 4194304) { src = k;  base = 2097152; }
  else if (i < 6291456) { src = v;  base = 4194304; }
  else if (i < 7340032) { src = wq; base = 6291456; }
  else if (i < 7602176) { src = wk; base = 7340032; }
  else if (i < 7864320) { src = wv; base = 7602176; }
  else                  { src = wo; base = 7864320; }
  float4 val = ((const float4*)src)[i - base];
  ushort4 o;
  o.x = f2bf(val.x); o.y = f2bf(val.y); o.z = f2bf(val.z); o.w = f2bf(val.w);
  ((ushort4*)dst)[i] = o;
}

// ---------------- shared GEMM K-loop: 2-phase double-buffered (T3 minimum) ----
// Old structure exposed the full staging latency per iter (issue -> drain
// barrier -> compute). Now: stage(t+1) is issued BEFORE compute(t); the single
// per-iter __syncthreads() (compiler emits vmcnt(0) before s_barrier) drains
// it AFTER compute -> HBM/L2 latency hides under the 16 MFMAs. One barrier
// per iter instead of two. Staging pattern + fragment reads are byte-identical
// to the R1-verified BK=32 code; As/Bs are 2x4096-short double buffers (32 KB
// total -> (256,3) keeps all 768 proj blocks resident, no tail round).
__device__ __forceinline__ void gemm_kloop(const unsigned short* __restrict__ A,
                                           const unsigned short* __restrict__ W,
                                           unsigned short* As, unsigned short* Bs,
                                           int bm, int bn, int K,
                                           int wm, int wn, int tid, int l16, int quad,
                                           f32x4 acc[4][4]) {
  auto stage = [&](int k0, int buf) {
    unsigned short* Ad = As + buf * 4096;
    unsigned short* Bd = Bs + buf * 4096;
#pragma unroll
    for (int r = 0; r < 2; ++r) {
      int c = r * 256 + tid;
      int row = c >> 2, c8 = (c & 3) << 3;
      g2l16(A + (size_t)(bm + row) * K + k0 + c8, (char*)Ad + (size_t)c * 16);
    }
#pragma unroll
    for (int r = 0; r < 2; ++r) {
      int c = r * 256 + tid;
      int row = c >> 2, c8 = (c & 3) << 3;
      g2l16(W + (size_t)(bn + row) * K + k0 + c8, (char*)Bd + (size_t)c * 16);
    }
  };

  stage(0, 0);
  __syncthreads();  // prologue drain: buf0 ready

  const int niter = K >> 5;
  for (int t = 0; t < niter; ++t) {
    if (t + 1 < niter) stage((t + 1) << 5, (t + 1) & 1);  // async prefetch

    const unsigned short* Ab = As + (t & 1) * 4096;
    const unsigned short* Bb = Bs + (t & 1) * 4096;
    bf16x8 af[4], bf[4];
#pragma unroll
    for (int mi = 0; mi < 4; ++mi)
      af[mi] = *(const bf16x8*)(Ab + (wm + mi * 16 + l16) * 32 + quad * 8);
#pragma unroll
    for (int ni = 0; ni < 4; ++ni)
      bf[ni] = *(const bf16x8*)(Bb + (wn + ni * 16 + l16) * 32 + quad * 8);
#pragma unroll
    for (int mi = 0; mi < 4; ++mi)
#pragma unroll
      for (int ni = 0; ni < 4; ++ni)
        acc[mi][ni] = __builtin_amdgcn_mfma_f32_16x16x32_bf16(af[mi], bf[ni], acc[mi][ni], 0, 0, 0);

    __syncthreads();  // drains prefetch (vmcnt 0) + all reads of buf[t&1] done
  }
}

// ---------------- fused Q/K/V projection ----------------
__global__ __launch_bounds__(256, 3)
void proj_fused(const unsigned short* __restrict__ qb, const unsigned short* __restrict__ kb,
                const unsigned short* __restrict__ vb,
                const unsigned short* __restrict__ Wqb, const unsigned short* __restrict__ Wkb,
                const unsigned short* __restrict__ Wvb,
                const float* __restrict__ bq, const float* __restrict__ bk,
                const float* __restrict__ bv,
                unsigned short* __restrict__ Qb, unsigned short* __restrict__ Kpp,
                unsigned short* __restrict__ Vtt) {
  __shared__ unsigned short As[2 * 128 * 32];  // double-buffered: 16 KB
  __shared__ unsigned short Bs[2 * 128 * 32];  // double-buffered: 16 KB
  const int tid  = threadIdx.x;
  const int wave = tid >> 6, lane = tid & 63;
  const int l16  = lane & 15, quad = lane >> 4;
  const int bm = blockIdx.x * 128;
  const int wm = (wave & 1) * 64, wn = (wave >> 1) * 64;
  const int y = blockIdx.y;

  const unsigned short *A, *W;
  const float* bias;
  unsigned short* out;
  int bn, mode, Nn;
  float scale;
  if (y < 16)      { A = qb; W = Wqb; bias = bq; out = Qb;  bn = y * 128;        mode = 0; Nn = 2048; scale = QSC;  }
  else if (y < 20) { A = kb; W = Wkb; bias = bk; out = Kpp; bn = (y - 16) * 128; mode = 0; Nn = 512;  scale = 1.0f; }
  else             { A = vb; W = Wvb; bias = bv; out = Vtt; bn = (y - 20) * 128; mode = 1; Nn = 512;  scale = 1.0f; }

  f32x4 acc[4][4] = {};
  gemm_kloop(A, W, As, Bs, bm, bn, E_, wm, wn, tid, l16, quad, acc);

  if (mode == 0) {
#pragma unroll
    for (int mi = 0; mi < 4; ++mi)
#pragma unroll
      for (int ni = 0; ni < 4; ++ni) {
        int col = bn + wn + ni * 16 + l16;
        float bb = bias[col];
        int row0 = bm + wm + mi * 16 + quad * 4;
#pragma unroll
        for (int r = 0; r < 4; ++r)
          out[(size_t)(row0 + r) * Nn + col] = f2bf((acc[mi][ni][r] + bb) * scale);
      }
  } else {  // V: transposed per batch -> Vt[(b*KVE + col)*N + s]
#pragma unroll
    for (int mi = 0; mi < 4; ++mi)
#pragma unroll
      for (int ni = 0; ni < 4; ++ni) {
        int col = bn + wn + ni * 16 + l16;
        float bb = bias[col];
        int row0 = bm + wm + mi * 16 + quad * 4;
        int b = row0 >> 11, s = row0 & 2047;
        ushort4 o;
        o.x = f2bf(acc[mi][ni][0] + bb);
        o.y = f2bf(acc[mi][ni][1] + bb);
        o.z = f2bf(acc[mi][ni][2] + bb);
        o.w = f2bf(acc[mi][ni][3] + bb);
        *(ushort4*)(out + (size_t)(b * KVE_ + col) * N_ + s) = o;
      }
  }
}

// ---------------- output projection (fp32 out) ----------------
__global__ __launch_bounds__(256, 3)
void gemm_out(const unsigned short* __restrict__ A, const unsigned short* __restrict__ W,
              const float* __restrict__ bias, float* __restrict__ Cout) {
  __shared__ unsigned short As[2 * 128 * 32];
  __shared__ unsigned short Bs[2 * 128 * 32];
  const int tid  = threadIdx.x;
  const int wave = tid >> 6, lane = tid & 63;
  const int l16  = lane & 15, quad = lane >> 4;
  const int bm = blockIdx.x * 128, bn = blockIdx.y * 128;
  const int wm = (wave & 1) * 64, wn = (wave >> 1) * 64;

  f32x4 acc[4][4] = {};
  gemm_kloop(A, W, As, Bs, bm, bn, E_, wm, wn, tid, l16, quad, acc);

#pragma unroll
  for (int mi = 0; mi < 4; ++mi)
#pragma unroll
    for (int ni = 0; ni < 4; ++ni) {
      int col = bn + wn + ni * 16 + l16;
      float bb = bias[col];
      int row0 = bm + wm + mi * 16 + quad * 4;
#pragma unroll
      for (int r = 0; r < 4; ++r)
        Cout[(size_t)(row0 + r) * E_ + col] = acc[mi][ni][r] + bb;
    }
}

// ---------------- Flash attention (R1-verified version, reverted verbatim) ----
// 32-key KV tiles, LDS 32 KB, each wave owns 16 q rows x full key range.
// Grid (32,32); launch_bounds(256,4). Measured: 82 us, VGPR 48, no spill.
__global__ __launch_bounds__(256, 4)
void attn_gqa(const unsigned short* __restrict__ Qp,
              const unsigned short* __restrict__ Kp,
              const unsigned short* __restrict__ Vt,
              unsigned short* __restrict__ Ob,
              const int* __restrict__ is_causal_p) {
  __shared__ unsigned short lds[2][8192];  // [buf][ K:4096 shorts | V:4096 shorts ] = 32KB

  const int tid  = threadIdx.x;
  const int wave = tid >> 6, lane = tid & 63;
  const int l16  = lane & 15, quad = lane >> 4;
  const int bh = blockIdx.y;
  const int u  = (blockIdx.x + bh) & 31;
  const int qt = (u < 16) ? u : 47 - u;   // 64-row q-tile; balanced per-CU sum
  const int b = bh >> 4, hq = bh & 15, hk = hq >> 2;
  const int causal = *is_causal_p;

  const unsigned short* Kbase = Kp + (size_t)b * N_ * KVE_ + hk * D_;
  const unsigned short* Vbase = Vt + (size_t)(b * KVE_ + hk * D_) * N_;

  const int nt = causal ? 2 * qt + 2 : (N_ / 32);  // 32-key tiles
  const int qw = qt * 64 + wave * 16;              // wave's 16-q window start

  // fragment-major staging: K block (sblk,kk) at shorts ((sblk*4+kk)*64+lane)*8
  // (lane reads K[s=sblk*16+l16][d=kk*32+quad*8..+7] -> A-operand);
  // V block dblk at 4096 + (dblk*64+lane)*8
  // (lane reads V^T[d=dblk*16+l16][s=quad*8..+7] -> A-operand).
  auto stage = [&](int t, int buf) {
    int s0 = t * 32;
    unsigned short* Kd = &lds[buf][0];
    unsigned short* Vd = &lds[buf][4096];
#pragma unroll
    for (int r = 0; r < 2; ++r) {
      int idx = r * 256 + tid;
      int s = (idx >> 8) * 16 + (idx & 15);
      int d = ((idx >> 6) & 3) * 32 + ((idx >> 4) & 3) * 8;
      g2l16(Kbase + (size_t)(s0 + s) * KVE_ + d, Kd + (size_t)idx * 8);
    }
#pragma unroll
    for (int r = 0; r < 2; ++r) {
      int idx = r * 256 + tid;
      int d = (idx >> 6) * 16 + (idx & 15);
      int sc = ((idx >> 4) & 3) * 8;
      g2l16(Vbase + (size_t)d * N_ + s0 + sc, Vd + (size_t)idx * 8);
    }
  };

  // Q fragments (B-operand: n=l16 -> q, k=quad*8+j -> d), exp2-scaled already
  bf16x8 qf[4];
#pragma unroll
  for (int kk = 0; kk < 4; ++kk)
    qf[kk] = *(const bf16x8*)(Qp + (size_t)(b * N_ + qw + l16) * E_ +
                              hq * D_ + kk * 32 + quad * 8);

  f32x4 o[8] = {};
  float tsum = 0.f;

  stage(0, 0);
  __syncthreads();

  for (int t = 0; t < nt; ++t) {
    if (t + 1 < nt) stage(t + 1, (t + 1) & 1);  // overlaps compute(t)
    const unsigned short* Kb = &lds[t & 1][0];
    const unsigned short* Vb = &lds[t & 1][4096];
    const int sw = t * 32;
    const bool active = !causal || (sw <= qw + 15);  // wave-uniform

    if (active) {
      // S^T = K Q^T : rows s = sw + ni*16+quad*4+r, cols q = qw + l16
      f32x4 sa[2] = {};
#pragma unroll
      for (int kk = 0; kk < 4; ++kk) {
        bf16x8 kf0 = *(const bf16x8*)(Kb + ((kk)     * 64 + lane) * 8);
        bf16x8 kf1 = *(const bf16x8*)(Kb + ((4 + kk) * 64 + lane) * 8);
        sa[0] = __builtin_amdgcn_mfma_f32_16x16x32_bf16(kf0, qf[kk], sa[0], 0, 0, 0);
        sa[1] = __builtin_amdgcn_mfma_f32_16x16x32_bf16(kf1, qf[kk], sa[1], 0, 0, 0);
      }

      if (causal && sw + 31 > qw) {  // diagonal overlap: mask s > q
        int q = qw + l16;
#pragma unroll
        for (int ni = 0; ni < 2; ++ni) {
          int sbase = sw + ni * 16 + quad * 4;
#pragma unroll
          for (int r = 0; r < 4; ++r)
            if (sbase + r > q) sa[ni][r] = -3.0e38f;
        }
      }

      // P = exp2(S) (no max subtraction), pack to bf16 pairs in-register
      uint32_t pk[2][2];
#pragma unroll
      for (int ni = 0; ni < 2; ++ni) {
#pragma unroll
        for (int r = 0; r < 4; ++r) {
          float e = __builtin_amdgcn_exp2f(sa[ni][r]);
          tsum += e;
          sa[ni][r] = e;
        }
        pk[ni][0] = pack_bf2(sa[ni][0], sa[ni][1]);
        pk[ni][1] = pack_bf2(sa[ni][2], sa[ni][3]);
      }

      // B-operand P[k=quad*8+j][n=l16] via shuffle network (unchanged mapping)
      union { bf16x8 v; uint32_t w[4]; } pb;
#pragma unroll
      for (int h = 0; h < 4; ++h) {
        int src = ((quad & 1) * 2 + (h >> 1)) * 16 + l16;
        uint32_t v0 = __shfl(pk[0][h & 1], src);
        uint32_t v1 = __shfl(pk[1][h & 1], src);
        pb.w[h] = (quad & 2) ? v1 : v0;
      }

      // O^T += V^T[:, sw:sw+32] P^T[sw:sw+32, :] — one K=32 MFMA step per d-block
      bf16x8 vf[8];
#pragma unroll
      for (int n8 = 0; n8 < 8; ++n8)
        vf[n8] = *(const bf16x8*)(Vb + (n8 * 64 + lane) * 8);
#pragma unroll
      for (int n8 = 0; n8 < 8; ++n8)
        o[n8] = __builtin_amdgcn_mfma_f32_16x16x32_bf16(vf[n8], pb.v, o[n8], 0, 0, 0);
    }
    __syncthreads();  // drains stage(t+1); protects buffer reuse
  }

  // ---- epilogue: pure-register; full row-sum via quad reduction ----
  float lt = tsum;
  lt += __shfl_xor(lt, 16);
  lt += __shfl_xor(lt, 32);
  float inv = 1.0f / lt;
  int q = qw + l16;
#pragma unroll
  for (int n8 = 0; n8 < 8; ++n8) {
    ushort4 st;
    st.x = f2bf(o[n8][0] * inv);
    st.y = f2bf(o[n8][1] * inv);
    st.z = f2bf(o[n8][2] * inv);
    st.w = f2bf(o[n8][3] * inv);
    *(ushort4*)(Ob + (size_t)(b * N_ + q) * E_ + hq * D_ + n8 * 16 + quad * 4) = st;
  }
}

// ---------------- host ----------------
extern "C" void kernel_launch(void* const* d_in, const int* in_sizes, int n_in,
                              void* d_out, int out_size, void* d_ws, size_t ws_size,
                              hipStream_t stream) {
  const float* query = (const float*)d_in[0];
  const float* key   = (const float*)d_in[1];
  const float* value = (const float*)d_in[2];
  const float* Wq = (const float*)d_in[3];
  const float* bq = (const float*)d_in[4];
  const float* Wk = (const float*)d_in[5];
  const float* bk = (const float*)d_in[6];
  const float* Wv = (const float*)d_in[7];
  const float* bv = (const float*)d_in[8];
  const float* Wo = (const float*)d_in[9];
  const float* bo = (const float*)d_in[10];
  const int* is_causal = (const int*)d_in[11];

  char* ws = (char*)d_ws;
  size_t off = 0;
  auto alloc = [&](size_t bytes) {
    char* p = ws + off;
    off += (bytes + 255) & ~(size_t)255;
    return p;
  };
  // NOTE: qb..Wob must stay contiguous in this order (cast_all writes one region)
  unsigned short* qb  = (unsigned short*)alloc((size_t)MTOT * E_ * 2);
  unsigned short* kb  = (unsigned short*)alloc((size_t)MTOT * E_ * 2);
  unsigned short* vb  = (unsigned short*)alloc((size_t)MTOT * E_ * 2);
  unsigned short* Wqb = (unsigned short*)alloc((size_t)E_ * E_ * 2);
  unsigned short* Wkb = (unsigned short*)alloc((size_t)KVE_ * E_ * 2);
  unsigned short* Wvb = (unsigned short*)alloc((size_t)KVE_ * E_ * 2);
  unsigned short* Wob = (unsigned short*)alloc((size_t)E_ * E_ * 2);
  unsigned short* Qb  = (unsigned short*)alloc((size_t)MTOT * E_ * 2);
  unsigned short* Kpp = (unsigned short*)alloc((size_t)MTOT * KVE_ * 2);
  unsigned short* Vtt = (unsigned short*)alloc((size_t)MTOT * KVE_ * 2);
  unsigned short* Ob  = (unsigned short*)alloc((size_t)MTOT * E_ * 2);
  (void)ws_size; (void)n_in; (void)in_sizes; (void)out_size;

  dim3 blk(256);
  cast_all<<<dim3(34816), blk, 0, stream>>>(query, key, value, Wq, Wk, Wv, Wo, qb);
  proj_fused<<<dim3(32, 24), blk, 0, stream>>>(qb, kb, vb, Wqb, Wkb, Wvb,
                                               bq, bk, bv, Qb, Kpp, Vtt);
  attn_gqa<<<dim3(32, 32), blk, 0, stream>>>(Qb, Kpp, Vtt, Ob, is_causal);
  gemm_out<<<dim3(32, 16), blk, 0, stream>>>(Ob, Wob, bo, (float*)d_out);
}